// Round 1
// baseline (1669.370 us; speedup 1.0000x reference)
//
#include <hip/hip_runtime.h>
#include <math.h>

namespace {
constexpr int kB = 1024;
constexpr int kC = 256;
constexpr int kH = 16;
constexpr int kW = 24;
constexpr int kHW = kH * kW;       // 384
constexpr int kN = 10;
constexpr int kD = 256;
constexpr int kHWTiles = kHW / 64; // 6
}

// Kernel 1: fused[b][hw][d] = relu( sum_c x[b,c,hw] * convw[c,d] + convb[d] )
// x = concat(input (256 ch), xcoord, ycoord)  -> K = 258 (coords folded in epilogue)
// Register-tiled f32 GEMM: block tile M=256(d) x N=64(hw), thread tile 8x8.
__global__ __launch_bounds__(256, 4)
void conv_fuse_kernel(const float* __restrict__ input,
                      const float* __restrict__ convw,
                      const float* __restrict__ convb,
                      float* __restrict__ fused)
{
    const int tid = threadIdx.x;
    const int b   = blockIdx.x / kHWTiles;
    const int hw0 = (blockIdx.x % kHWTiles) * 64;
    const int tm = tid >> 3;   // 0..31  -> d block of 8
    const int tn = tid & 7;    // 0..7   -> hw block of 8

    __shared__ float Wl[32][256];  // 32 KB
    __shared__ float Xl[32][64];   // 8 KB

    float acc[8][8];
#pragma unroll
    for (int i = 0; i < 8; ++i)
#pragma unroll
        for (int j = 0; j < 8; ++j) acc[i][j] = 0.0f;

    const size_t inBase = (size_t)b * (kC * kHW);

    for (int k0 = 0; k0 < 256; k0 += 32) {
        __syncthreads();
        // stage W tile (contiguous 32x256 chunk), fully coalesced float4
        {
            const float4* wsrc = reinterpret_cast<const float4*>(convw + (size_t)k0 * 256);
            float4* wdst = reinterpret_cast<float4*>(&Wl[0][0]);
#pragma unroll
            for (int p = 0; p < 8; ++p) wdst[p * 256 + tid] = wsrc[p * 256 + tid];
        }
        // stage X tile: 32 rows (c) x 64 cols (hw), rows are 256B contiguous
        {
#pragma unroll
            for (int p = 0; p < 2; ++p) {
                int idx = p * 256 + tid;
                int r = idx >> 4, c4 = idx & 15;
                const float4* xsrc = reinterpret_cast<const float4*>(
                    input + inBase + (size_t)(k0 + r) * kHW + hw0);
                reinterpret_cast<float4*>(&Xl[r][0])[c4] = xsrc[c4];
            }
        }
        __syncthreads();
#pragma unroll
        for (int k = 0; k < 32; ++k) {
            float4 a0 = *reinterpret_cast<const float4*>(&Wl[k][tm * 8]);
            float4 a1 = *reinterpret_cast<const float4*>(&Wl[k][tm * 8 + 4]);
            float4 x0 = *reinterpret_cast<const float4*>(&Xl[k][tn * 8]);
            float4 x1 = *reinterpret_cast<const float4*>(&Xl[k][tn * 8 + 4]);
            float av[8] = {a0.x, a0.y, a0.z, a0.w, a1.x, a1.y, a1.z, a1.w};
            float xv[8] = {x0.x, x0.y, x0.z, x0.w, x1.x, x1.y, x1.z, x1.w};
#pragma unroll
            for (int mi = 0; mi < 8; ++mi)
#pragma unroll
                for (int ni = 0; ni < 8; ++ni)
                    acc[mi][ni] = fmaf(av[mi], xv[ni], acc[mi][ni]);
        }
    }

    // epilogue: coord channels (k=256: xcoord, k=257: ycoord) + bias + relu
    const int d0 = tm * 8;
    float wx[8], wy[8], bb[8];
#pragma unroll
    for (int mi = 0; mi < 8; ++mi) {
        wx[mi] = convw[256 * 256 + d0 + mi];
        wy[mi] = convw[257 * 256 + d0 + mi];
        bb[mi] = convb[d0 + mi];
    }
    float xcv[8], ycv[8];
#pragma unroll
    for (int ni = 0; ni < 8; ++ni) {
        int hw = hw0 + tn * 8 + ni;
        int row = hw / kW, col = hw % kW;      // linspace(0,1,W)[col], linspace(0,1,H)[row]
        xcv[ni] = (float)col * (1.0f / 23.0f);
        ycv[ni] = (float)row * (1.0f / 15.0f);
    }
    float* outb = fused + ((size_t)b * kHW + hw0) * 256;   // layout [B][HW][C]
#pragma unroll
    for (int ni = 0; ni < 8; ++ni) {
        int hw = tn * 8 + ni;
        float o[8];
#pragma unroll
        for (int mi = 0; mi < 8; ++mi) {
            float v = acc[mi][ni] + wx[mi] * xcv[ni] + wy[mi] * ycv[ni] + bb[mi];
            o[mi] = fmaxf(v, 0.0f);
        }
        float4* dst = reinterpret_cast<float4*>(outb + (size_t)hw * 256 + d0);
        dst[0] = make_float4(o[0], o[1], o[2], o[3]);
        dst[1] = make_float4(o[4], o[5], o[6], o[7]);
    }
}

// Kernel 2: per-batch block. scores -> softmax -> vals -> reps(+norm+mask) -> o1/o2 -> pair.
__global__ __launch_bounds__(256, 2)
void scene_rest_kernel(const float* __restrict__ fused,
                       const int* __restrict__ lenRaw,
                       const float* __restrict__ query,
                       const float* __restrict__ featw,
                       const float* __restrict__ featb,
                       const float* __restrict__ o1w,
                       const float* __restrict__ o1b,
                       const float* __restrict__ o2w,
                       const float* __restrict__ o2b,
                       float* __restrict__ outReps,
                       float* __restrict__ outPair)
{
    const int b = blockIdx.x;
    const int tid = threadIdx.x;
    const int lane = tid & 63;
    const int wv = tid >> 6;

    __shared__ float q_lds[kN][256];
    __shared__ float sc[kN][kHW];
    __shared__ float v_lds[kN][256];
    __shared__ float r_lds[kN][256];
    __shared__ float o1_lds[kN][256];
    __shared__ float o2_lds[kN][256];

    // objects_length may be int64 (ref casts) or int32 (jax x64 off).
    // values are in [1,10]; i32 view: int64 layout has high word 0 at index 1.
    const int is64 = (lenRaw[1] == 0) ? 1 : 0;
    const int len = is64 ? lenRaw[2 * b] : lenRaw[b];

    for (int i = tid; i < kN * 256; i += 256) (&q_lds[0][0])[i] = query[i];
    __syncthreads();

    // phase 1: scores[n][hw] = q[n,:] . fused[b,hw,:]   (wave per hw row)
    const float4* f4 = reinterpret_cast<const float4*>(fused + (size_t)b * kHW * 256);
    const float4* q4 = reinterpret_cast<const float4*>(&q_lds[0][0]);
    for (int hw = wv; hw < kHW; hw += 4) {
        float4 f = f4[hw * 64 + lane];
#pragma unroll
        for (int n = 0; n < kN; ++n) {
            float4 q = q4[n * 64 + lane];
            float p = f.x * q.x + f.y * q.y + f.z * q.z + f.w * q.w;
#pragma unroll
            for (int off = 32; off >= 1; off >>= 1) p += __shfl_xor(p, off, 64);
            if (lane == 0) sc[n][hw] = p;
        }
    }
    __syncthreads();

    // phase 2: softmax over hw (wave per object row)
    for (int n = wv; n < kN; n += 4) {
        float v6[6];
        float m = -1e30f;
#pragma unroll
        for (int i = 0; i < 6; ++i) { v6[i] = sc[n][lane + 64 * i]; m = fmaxf(m, v6[i]); }
#pragma unroll
        for (int off = 32; off >= 1; off >>= 1) m = fmaxf(m, __shfl_xor(m, off, 64));
        float s = 0.0f;
#pragma unroll
        for (int i = 0; i < 6; ++i) { v6[i] = __expf(v6[i] - m); s += v6[i]; }
#pragma unroll
        for (int off = 32; off >= 1; off >>= 1) s += __shfl_xor(s, off, 64);
        float inv = 1.0f / s;
#pragma unroll
        for (int i = 0; i < 6; ++i) sc[n][lane + 64 * i] = v6[i] * inv;
    }
    __syncthreads();

    // phase 3: vals[n][c] = sum_hw attn[n][hw] * fused[b][hw][c]   (thread = c)
    {
        const float* fb = fused + (size_t)b * kHW * 256;
        float va[kN];
#pragma unroll
        for (int n = 0; n < kN; ++n) va[n] = 0.0f;
        for (int hw = 0; hw < kHW; ++hw) {
            float f = fb[(size_t)hw * 256 + tid];
#pragma unroll
            for (int n = 0; n < kN; ++n) va[n] = fmaf(sc[n][hw], f, va[n]);
        }
#pragma unroll
        for (int n = 0; n < kN; ++n) v_lds[n][tid] = va[n];
    }
    __syncthreads();

    // phase 4: reps[n][d] = relu(vals[n,:] @ featw[:,d] + featb[d])  (thread = d, weights read once)
    {
        float ra[kN];
        float fb0 = featb[tid];
#pragma unroll
        for (int n = 0; n < kN; ++n) ra[n] = fb0;
        for (int k = 0; k < 256; ++k) {
            float w = featw[k * 256 + tid];
#pragma unroll
            for (int n = 0; n < kN; ++n) ra[n] = fmaf(v_lds[n][k], w, ra[n]);
        }
#pragma unroll
        for (int n = 0; n < kN; ++n) r_lds[n][tid] = fmaxf(ra[n], 0.0f);
    }
    __syncthreads();

    // phase 5: L2-normalize + ragged mask + write reps
    {
        float4* r4 = reinterpret_cast<float4*>(&r_lds[0][0]);
        float4* or4 = reinterpret_cast<float4*>(outReps + (size_t)b * kN * 256);
        for (int n = wv; n < kN; n += 4) {
            float4 r = r4[n * 64 + lane];
            float ss = r.x * r.x + r.y * r.y + r.z * r.z + r.w * r.w;
#pragma unroll
            for (int off = 32; off >= 1; off >>= 1) ss += __shfl_xor(ss, off, 64);
            float norm = sqrtf(ss);
            float scale = (n < len) ? (1.0f / fmaxf(norm, 1e-12f)) : 0.0f;
            r.x *= scale; r.y *= scale; r.z *= scale; r.w *= scale;
            r4[n * 64 + lane] = r;
            or4[n * 64 + lane] = r;
        }
    }
    __syncthreads();

    // phase 6: o1 = reps@obj1_w + b1 ; o2 = reps@obj2_w + b2  (thread = d)
    {
        float a1[kN], a2[kN];
        float b1 = o1b[tid], b2 = o2b[tid];
#pragma unroll
        for (int n = 0; n < kN; ++n) { a1[n] = b1; a2[n] = b2; }
        for (int k = 0; k < 256; ++k) {
            float w1 = o1w[k * 256 + tid];
            float w2 = o2w[k * 256 + tid];
#pragma unroll
            for (int n = 0; n < kN; ++n) {
                float r = r_lds[n][k];
                a1[n] = fmaf(r, w1, a1[n]);
                a2[n] = fmaf(r, w2, a2[n]);
            }
        }
#pragma unroll
        for (int n = 0; n < kN; ++n) { o1_lds[n][tid] = a1[n]; o2_lds[n][tid] = a2[n]; }
    }
    __syncthreads();

    // phase 7: pair[i][j][d] = mask_i*mask_j * (o1[i][d] + o2[j][d])
    {
        float* pb = outPair + (size_t)b * kN * kN * 256;
#pragma unroll
        for (int i = 0; i < kN; ++i) {
            float o1v = o1_lds[i][tid];
            bool mvalid = (i < len);
#pragma unroll
            for (int j = 0; j < kN; ++j) {
                float v = (mvalid && (j < len)) ? (o1v + o2_lds[j][tid]) : 0.0f;
                pb[(size_t)(i * kN + j) * 256 + tid] = v;
            }
        }
    }
}

extern "C" void kernel_launch(void* const* d_in, const int* in_sizes, int n_in,
                              void* d_out, int out_size, void* d_ws, size_t ws_size,
                              hipStream_t stream) {
    const float* input = (const float*)d_in[0];
    // d_in[1] objects: unused by the reference computation
    const int*   lenRaw = (const int*)d_in[2];
    const float* query  = (const float*)d_in[3];
    const float* convw  = (const float*)d_in[4];
    const float* convb  = (const float*)d_in[5];
    const float* featw  = (const float*)d_in[6];
    const float* featb  = (const float*)d_in[7];
    const float* o1w    = (const float*)d_in[8];
    const float* o1b    = (const float*)d_in[9];
    const float* o2w    = (const float*)d_in[10];
    const float* o2b    = (const float*)d_in[11];

    float* fused = (float*)d_ws;                    // [B][HW][C] f32 = 402.7 MB
    float* outReps = (float*)d_out;                 // [B][N][D]
    float* outPair = outReps + (size_t)kB * kN * kD;// [B][N][N][D]

    conv_fuse_kernel<<<kB * kHWTiles, 256, 0, stream>>>(input, convw, convb, fused);
    scene_rest_kernel<<<kB, 256, 0, stream>>>(fused, lenRaw, query, featw, featb,
                                              o1w, o1b, o2w, o2b, outReps, outPair);
}

// Round 2
// 1126.063 us; speedup vs baseline: 1.4825x; 1.4825x over previous
//
#include <hip/hip_runtime.h>
#include <math.h>

typedef __attribute__((ext_vector_type(8))) short bf16x8;
typedef __attribute__((ext_vector_type(4))) float f32x4;

namespace {
constexpr int kB = 1024;
constexpr int kHW = 384;
constexpr int kN = 10;
constexpr int kD = 256;
}

__device__ inline void split_bf16(float x, unsigned short& hi, unsigned short& lo) {
    unsigned u = __float_as_uint(x);
    unsigned r = (u + 0x7fffu + ((u >> 16) & 1u)) & 0xffff0000u;   // RNE to bf16
    hi = (unsigned short)(r >> 16);
    float res = x - __uint_as_float(r);                            // exact
    unsigned u2 = __float_as_uint(res);
    lo = (unsigned short)((u2 + 0x7fffu + ((u2 >> 16) & 1u)) >> 16);
}

__device__ inline void gload16(void* lds, const void* g) {
    __builtin_amdgcn_global_load_lds((const __attribute__((address_space(1))) unsigned int*)g,
                                     (__attribute__((address_space(3))) unsigned int*)lds,
                                     16, 0, 0);
}

// ---------------------------------------------------------------------------
// W-prep: split convw[0:256][256] into hi/lo bf16, stored TRANSPOSED [n][k] in
// gload_lds-ready tiles with the XOR-swizzle pre-applied to the layout.
// Tile (ntile 0..1, kstep 0..7): u16 idx = (ntile*8+kstep)*4096 + n_loc*32 + i16,
// holding element (n = ntile*128+n_loc, k = kstep*32 + (i16 ^ ((n_loc&3)<<3))).
// ---------------------------------------------------------------------------
__global__ void wprep_kernel(const float* __restrict__ convw,
                             unsigned short* __restrict__ Whs,
                             unsigned short* __restrict__ Wls) {
    int i = blockIdx.x * 256 + threadIdx.x;   // 64 blocks * 256 = 16384 threads
    for (; i < 65536; i += 16384) {
        int tile = i >> 12;
        int nt = tile >> 3, kstep = tile & 7;
        int rem = i & 4095;
        int n_loc = rem >> 5, i16 = rem & 31;
        int k = kstep * 32 + (i16 ^ ((n_loc & 3) << 3));
        int n = nt * 128 + n_loc;
        unsigned short h, l;
        split_bf16(convw[k * 256 + n], h, l);
        Whs[i] = h;
        Wls[i] = l;
    }
}

// ---------------------------------------------------------------------------
// Conv as split-bf16 MFMA GEMM: fused[b][hw][d] = relu(X^T W + coords + bias)
// M = B*HW (tiles of 128 hw, aligned within a batch: 384 = 3*128),
// N = 256 (2 tiles of 128), K = 256 (8 steps of 32). 3 MFMA products per frag.
// A (input) transposed+split in-kernel: raw f32 tile gload_lds -> LDS linear
// [k][m] -> column reads (conflict-free) -> cvt/split -> swizzled b128 writes.
// LDS element (m,k) at byte m*64 + ((2k) ^ ((m&3)<<4)); frag read b128 at
// m*64 + ((16*kq) ^ ((m&3)<<4)).
// ---------------------------------------------------------------------------
__global__ __launch_bounds__(256, 2)
void conv_mfma_kernel(const float* __restrict__ input,
                      const unsigned short* __restrict__ Whs,
                      const unsigned short* __restrict__ Wls,
                      const float* __restrict__ convw,
                      const float* __restrict__ convb,
                      float* __restrict__ fused) {
    __shared__ unsigned short Ah[128 * 32];
    __shared__ unsigned short Al[128 * 32];
    __shared__ unsigned short Bh[128 * 32];
    __shared__ unsigned short Bl[128 * 32];
    __shared__ float Raw[2][32 * 128];

    const int tid = threadIdx.x;
    const int lane = tid & 63;
    const int wid = tid >> 6;
    const int wr = wid >> 1, wc = wid & 1;     // 2x2 wave grid, wave tile 64x64
    const int kq = lane >> 4, lr = lane & 15;

    const int mtile = blockIdx.x >> 1;
    const int ntile = blockIdx.x & 1;
    const int b = mtile / 3;
    const int hw0 = (mtile % 3) * 128;

    const int sm = tid >> 1;          // staging: m row 0..127
    const int skh = (tid & 1) * 16;   // staging: k half

    f32x4 acc[4][4];
#pragma unroll
    for (int i = 0; i < 4; ++i)
#pragma unroll
        for (int j = 0; j < 4; ++j) acc[i][j] = (f32x4){0.f, 0.f, 0.f, 0.f};

    const size_t inBase = ((size_t)b * 256) * 384 + hw0;

    auto issue_raw = [&](int ks, int buf) {
#pragma unroll
        for (int rd = 0; rd < 4; ++rd) {
            int o = tid * 16 + rd * 4096;            // 16 KB raw tile
            int r = o >> 9;                          // k row 0..31
            int inb = o & 511;                       // byte within 512B row seg
            gload16((char*)&Raw[buf][0] + o,
                    (const char*)(input + inBase + (size_t)(ks * 32 + r) * 384) + inb);
        }
    };
    auto issue_B = [&](int ks) {
        const char* srcH = (const char*)(Whs + (size_t)(ntile * 8 + ks) * 4096);
        const char* srcL = (const char*)(Wls + (size_t)(ntile * 8 + ks) * 4096);
#pragma unroll
        for (int rd = 0; rd < 2; ++rd) {
            int o = tid * 16 + rd * 4096;
            gload16((char*)Bh + o, srcH + o);
            gload16((char*)Bl + o, srcL + o);
        }
    };
    auto cvt_write_A = [&](int buf) {
        float v[16];
#pragma unroll
        for (int j = 0; j < 16; ++j) v[j] = Raw[buf][(skh + j) * 128 + sm];
        unsigned hw_[8], lw_[8];
#pragma unroll
        for (int j = 0; j < 8; ++j) {
            unsigned short h0, l0, h1, l1;
            split_bf16(v[2 * j], h0, l0);
            split_bf16(v[2 * j + 1], h1, l1);
            hw_[j] = (unsigned)h0 | ((unsigned)h1 << 16);
            lw_[j] = (unsigned)l0 | ((unsigned)l1 << 16);
        }
        const int s = (sm & 3) << 4;
        char* bh = (char*)Ah + sm * 64;
        char* bl = (char*)Al + sm * 64;
        *(uint4*)(bh + (((2 * skh)) ^ s))      = make_uint4(hw_[0], hw_[1], hw_[2], hw_[3]);
        *(uint4*)(bh + (((2 * skh) + 16) ^ s)) = make_uint4(hw_[4], hw_[5], hw_[6], hw_[7]);
        *(uint4*)(bl + (((2 * skh)) ^ s))      = make_uint4(lw_[0], lw_[1], lw_[2], lw_[3]);
        *(uint4*)(bl + (((2 * skh) + 16) ^ s)) = make_uint4(lw_[4], lw_[5], lw_[6], lw_[7]);
    };

    // prologue: raw(0), B(0) in flight; convert A(0); raw(1) in flight
    issue_raw(0, 0);
    issue_B(0);
    __syncthreads();          // drains vmcnt: raw(0) + B(0) landed
    cvt_write_A(0);
    issue_raw(1, 1);
    __syncthreads();          // A(0) tiles written (raw(1)/B pending ok)

    for (int ks = 0; ks < 8; ++ks) {
        bf16x8 afh[4], afl[4], bfh[4], bfl[4];
#pragma unroll
        for (int fm = 0; fm < 4; ++fm) {
            int m = wr * 64 + fm * 16 + lr;
            int a = m * 64 + ((16 * kq) ^ ((m & 3) << 4));
            afh[fm] = *(const bf16x8*)((const char*)Ah + a);
            afl[fm] = *(const bf16x8*)((const char*)Al + a);
        }
#pragma unroll
        for (int fn = 0; fn < 4; ++fn) {
            int n = wc * 64 + fn * 16 + lr;
            int a = n * 64 + ((16 * kq) ^ ((n & 3) << 4));
            bfh[fn] = *(const bf16x8*)((const char*)Bh + a);
            bfl[fn] = *(const bf16x8*)((const char*)Bl + a);
        }
        __syncthreads();      // all frag reads done -> tiles may be overwritten
        if (ks < 7) {
            cvt_write_A((ks + 1) & 1);   // raw(ks+1) already drained by barrier
            if (ks < 6) issue_raw(ks + 2, ks & 1);
            issue_B(ks + 1);
        }
#pragma unroll
        for (int fn = 0; fn < 4; ++fn)
#pragma unroll
            for (int fm = 0; fm < 4; ++fm) {
                acc[fm][fn] = __builtin_amdgcn_mfma_f32_16x16x32_bf16(afh[fm], bfh[fn], acc[fm][fn], 0, 0, 0);
                acc[fm][fn] = __builtin_amdgcn_mfma_f32_16x16x32_bf16(afl[fm], bfh[fn], acc[fm][fn], 0, 0, 0);
                acc[fm][fn] = __builtin_amdgcn_mfma_f32_16x16x32_bf16(afh[fm], bfl[fn], acc[fm][fn], 0, 0, 0);
            }
        if (ks < 7) __syncthreads();   // staging(ks+1) complete
    }

    // epilogue: coord channels (k=256 x, k=257 y) + bias + relu
    float wxv[4], wyv[4], bbv[4];
#pragma unroll
    for (int fn = 0; fn < 4; ++fn) {
        int d = ntile * 128 + wc * 64 + fn * 16 + lr;
        wxv[fn] = convw[256 * 256 + d];
        wyv[fn] = convw[257 * 256 + d];
        bbv[fn] = convb[d];
    }
#pragma unroll
    for (int fm = 0; fm < 4; ++fm)
#pragma unroll
        for (int r = 0; r < 4; ++r) {
            int m = wr * 64 + fm * 16 + kq * 4 + r;   // D row = (lane>>4)*4 + reg
            int hw = hw0 + m;
            int row = hw / 24, col = hw % 24;
            float xc = (float)col * (1.0f / 23.0f);
            float yc = (float)row * (1.0f / 15.0f);
            size_t obase = ((size_t)b * 384 + hw) * 256;
#pragma unroll
            for (int fn = 0; fn < 4; ++fn) {
                int d = ntile * 128 + wc * 64 + fn * 16 + lr;  // D col = lane&15
                float v = acc[fm][fn][r] + wxv[fn] * xc + wyv[fn] * yc + bbv[fn];
                fused[obase + d] = fmaxf(v, 0.0f);
            }
        }
}

// ---------------------------------------------------------------------------
// Kernel 2: per-batch. scores -> softmax -> vals -> reps(+norm+mask) -> o1/o2
// -> pair. LDS cut to 46 KB (3 blocks/CU); phase-1 reductions interleaved.
// ---------------------------------------------------------------------------
__global__ __launch_bounds__(256, 3)
void scene_rest_kernel(const float* __restrict__ fused,
                       const int* __restrict__ lenRaw,
                       const float* __restrict__ query,
                       const float* __restrict__ featw,
                       const float* __restrict__ featb,
                       const float* __restrict__ o1w,
                       const float* __restrict__ o1b,
                       const float* __restrict__ o2w,
                       const float* __restrict__ o2b,
                       float* __restrict__ outReps,
                       float* __restrict__ outPair) {
    const int b = blockIdx.x;
    const int tid = threadIdx.x;
    const int lane = tid & 63;
    const int wv = tid >> 6;

    __shared__ float sc[kN][kHW];      // 15 KB: scores -> attn
    __shared__ float bufA[kN][256];    // vals (ph3-4), then o1 (ph6-7)
    __shared__ float bufR[kN][256];    // reps
    __shared__ float bufC[kN][256];    // o2

    // objects_length is int64 (ref casts) or int32; values in [1,10].
    const int is64 = (lenRaw[1] == 0) ? 1 : 0;
    const int len = is64 ? lenRaw[2 * b] : lenRaw[b];

    // phase 1: scores[n][hw] = q[n,:] . fused[b,hw,:]  (wave per hw row,
    // all 10 reductions interleaved -> shuffle depth 6 not 60)
    const float4* f4 = reinterpret_cast<const float4*>(fused + (size_t)b * kHW * 256);
    const float4* q4 = reinterpret_cast<const float4*>(query);
    for (int hw = wv; hw < kHW; hw += 4) {
        float4 f = f4[hw * 64 + lane];
        float p[kN];
#pragma unroll
        for (int n = 0; n < kN; ++n) {
            float4 q = q4[n * 64 + lane];
            p[n] = f.x * q.x + f.y * q.y + f.z * q.z + f.w * q.w;
        }
#pragma unroll
        for (int off = 32; off >= 1; off >>= 1)
#pragma unroll
            for (int n = 0; n < kN; ++n) p[n] += __shfl_xor(p[n], off, 64);
        if (lane == 0)
#pragma unroll
            for (int n = 0; n < kN; ++n) sc[n][hw] = p[n];
    }
    __syncthreads();

    // phase 2: softmax over hw (wave per object)
    for (int n = wv; n < kN; n += 4) {
        float v6[6];
        float m = -1e30f;
#pragma unroll
        for (int i = 0; i < 6; ++i) { v6[i] = sc[n][lane + 64 * i]; m = fmaxf(m, v6[i]); }
#pragma unroll
        for (int off = 32; off >= 1; off >>= 1) m = fmaxf(m, __shfl_xor(m, off, 64));
        float s = 0.0f;
#pragma unroll
        for (int i = 0; i < 6; ++i) { v6[i] = __expf(v6[i] - m); s += v6[i]; }
#pragma unroll
        for (int off = 32; off >= 1; off >>= 1) s += __shfl_xor(s, off, 64);
        float inv = 1.0f / s;
#pragma unroll
        for (int i = 0; i < 6; ++i) sc[n][lane + 64 * i] = v6[i] * inv;
    }
    __syncthreads();

    // phase 3: vals[n][c] = sum_hw attn[n][hw] * fused[b][hw][c]  (thread = c)
    {
        const float* fb = fused + (size_t)b * kHW * 256;
        float va[kN];
#pragma unroll
        for (int n = 0; n < kN; ++n) va[n] = 0.0f;
        for (int hw = 0; hw < kHW; ++hw) {
            float f = fb[(size_t)hw * 256 + tid];
#pragma unroll
            for (int n = 0; n < kN; ++n) va[n] = fmaf(sc[n][hw], f, va[n]);
        }
#pragma unroll
        for (int n = 0; n < kN; ++n) bufA[n][tid] = va[n];
    }
    __syncthreads();

    // phase 4: reps[n][d] = relu(vals @ featw + featb)  (thread = d)
    {
        float ra[kN];
        float fb0 = featb[tid];
#pragma unroll
        for (int n = 0; n < kN; ++n) ra[n] = fb0;
        for (int k = 0; k < 256; ++k) {
            float w = featw[k * 256 + tid];
#pragma unroll
            for (int n = 0; n < kN; ++n) ra[n] = fmaf(bufA[n][k], w, ra[n]);
        }
#pragma unroll
        for (int n = 0; n < kN; ++n) bufR[n][tid] = fmaxf(ra[n], 0.0f);
    }
    __syncthreads();

    // phase 5: L2-normalize + ragged mask + write reps
    {
        float4* r4 = reinterpret_cast<float4*>(&bufR[0][0]);
        float4* or4 = reinterpret_cast<float4*>(outReps + (size_t)b * kN * 256);
        for (int n = wv; n < kN; n += 4) {
            float4 r = r4[n * 64 + lane];
            float ss = r.x * r.x + r.y * r.y + r.z * r.z + r.w * r.w;
#pragma unroll
            for (int off = 32; off >= 1; off >>= 1) ss += __shfl_xor(ss, off, 64);
            float norm = sqrtf(ss);
            float scale = (n < len) ? (1.0f / fmaxf(norm, 1e-12f)) : 0.0f;
            r.x *= scale; r.y *= scale; r.z *= scale; r.w *= scale;
            r4[n * 64 + lane] = r;
            or4[n * 64 + lane] = r;
        }
    }
    __syncthreads();

    // phase 6: o1 = reps@obj1_w + b1 -> bufA ; o2 = reps@obj2_w + b2 -> bufC
    {
        float a1[kN], a2[kN];
        float b1 = o1b[tid], b2 = o2b[tid];
#pragma unroll
        for (int n = 0; n < kN; ++n) { a1[n] = b1; a2[n] = b2; }
        for (int k = 0; k < 256; ++k) {
            float w1 = o1w[k * 256 + tid];
            float w2 = o2w[k * 256 + tid];
#pragma unroll
            for (int n = 0; n < kN; ++n) {
                float r = bufR[n][k];
                a1[n] = fmaf(r, w1, a1[n]);
                a2[n] = fmaf(r, w2, a2[n]);
            }
        }
#pragma unroll
        for (int n = 0; n < kN; ++n) { bufA[n][tid] = a1[n]; bufC[n][tid] = a2[n]; }
    }
    __syncthreads();

    // phase 7: pair[i][j][d]
    {
        float* pb = outPair + (size_t)b * kN * kN * 256;
#pragma unroll
        for (int i = 0; i < kN; ++i) {
            float o1v = bufA[i][tid];
            bool mvalid = (i < len);
#pragma unroll
            for (int j = 0; j < kN; ++j) {
                float v = (mvalid && (j < len)) ? (o1v + bufC[j][tid]) : 0.0f;
                pb[(size_t)(i * kN + j) * 256 + tid] = v;
            }
        }
    }
}

extern "C" void kernel_launch(void* const* d_in, const int* in_sizes, int n_in,
                              void* d_out, int out_size, void* d_ws, size_t ws_size,
                              hipStream_t stream) {
    const float* input  = (const float*)d_in[0];
    const int*   lenRaw = (const int*)d_in[2];
    const float* query  = (const float*)d_in[3];
    const float* convw  = (const float*)d_in[4];
    const float* convb  = (const float*)d_in[5];
    const float* featw  = (const float*)d_in[6];
    const float* featb  = (const float*)d_in[7];
    const float* o1w    = (const float*)d_in[8];
    const float* o1b    = (const float*)d_in[9];
    const float* o2w    = (const float*)d_in[10];
    const float* o2b    = (const float*)d_in[11];

    float* fused   = (float*)d_ws;                    // [B][HW][C] f32 = 402.7 MB
    float* outReps = (float*)d_out;                   // [B][N][D]
    float* outPair = outReps + (size_t)kB * kN * kD;  // [B][N][N][D]

    // W split scratch (256 KB) parked in the pair region of d_out; it is
    // consumed by conv_mfma before scene_rest overwrites all of pair.
    unsigned short* Whs = (unsigned short*)outPair;
    unsigned short* Wls = Whs + 65536;

    wprep_kernel<<<64, 256, 0, stream>>>(convw, Whs, Wls);
    conv_mfma_kernel<<<6144, 256, 0, stream>>>(input, Whs, Wls, convw, convb, fused);
    scene_rest_kernel<<<kB, 256, 0, stream>>>(fused, lenRaw, query, featw, featb,
                                              o1w, o1b, o2w, o2b, outReps, outPair);
}

// Round 4
// 1017.553 us; speedup vs baseline: 1.6406x; 1.1066x over previous
//
#include <hip/hip_runtime.h>
#include <math.h>

typedef __attribute__((ext_vector_type(8))) short bf16x8;
typedef __attribute__((ext_vector_type(4))) float f32x4;

namespace {
constexpr int kB = 1024;
constexpr int kHW = 384;
constexpr int kN = 10;
constexpr int kD = 256;
constexpr int kC = 256;
constexpr size_t kPlane = (size_t)kB * kHW * kC;   // u16 elems per plane
}

// RNE split (used in wprep, proven in R1/R2)
__device__ inline void split_bf16(float x, unsigned short& hi, unsigned short& lo) {
    unsigned u = __float_as_uint(x);
    unsigned r = (u + 0x7fffu + ((u >> 16) & 1u)) & 0xffff0000u;
    hi = (unsigned short)(r >> 16);
    float res = x - __uint_as_float(r);
    unsigned u2 = __float_as_uint(res);
    lo = (unsigned short)((u2 + 0x7fffu + ((u2 >> 16) & 1u)) >> 16);
}

// cheap trunc split of a PAIR, packed: hi word = (h1|h0), lo word = (l1|l0)
// err: hi exact-trunc, residual < 2^-8 rel, lo trunc of residual -> 2^-16 rel total
__device__ inline void split2(float x0, float x1, unsigned& hi, unsigned& lo) {
    unsigned u0 = __float_as_uint(x0), u1 = __float_as_uint(x1);
    unsigned h0 = u0 & 0xffff0000u, h1 = u1 & 0xffff0000u;
    float r0 = x0 - __uint_as_float(h0);
    float r1 = x1 - __uint_as_float(h1);
    hi = (h0 >> 16) | h1;
    lo = (__float_as_uint(r0) >> 16) | (__float_as_uint(r1) & 0xffff0000u);
}

__device__ inline void split1(float x, unsigned short& h, unsigned short& l) {
    unsigned u = __float_as_uint(x);
    unsigned hb = u & 0xffff0000u;
    h = (unsigned short)(hb >> 16);
    float r = x - __uint_as_float(hb);
    l = (unsigned short)(__float_as_uint(r) >> 16);
}

__device__ inline float bfval(unsigned short u) {
    return __uint_as_float(((unsigned)u) << 16);
}

__device__ inline void gload16(void* lds, const void* g) {
    __builtin_amdgcn_global_load_lds((const __attribute__((address_space(1))) unsigned int*)g,
                                     (__attribute__((address_space(3))) unsigned int*)lds,
                                     16, 0, 0);
}

// ---------------------------------------------------------------------------
// W-prep (proven in R2): split convw[0:256][256] -> hi/lo bf16, transposed
// [n][k], swizzle pre-applied: u16 idx = tile*4096 + n_loc*32 + i16 holds
// (n = nt*128+n_loc, k = ks*32 + (i16 ^ ((n_loc&3)<<3))).
// ---------------------------------------------------------------------------
__global__ void wprep_kernel(const float* __restrict__ convw,
                             unsigned short* __restrict__ Whs,
                             unsigned short* __restrict__ Wls) {
    int i = blockIdx.x * 256 + threadIdx.x;
    for (; i < 65536; i += 16384) {
        int tile = i >> 12;
        int nt = tile >> 3, kstep = tile & 7;
        int rem = i & 4095;
        int n_loc = rem >> 5, i16 = rem & 31;
        int k = kstep * 32 + (i16 ^ ((n_loc & 3) << 3));
        int n = nt * 128 + n_loc;
        unsigned short h, l;
        split_bf16(convw[k * 256 + n], h, l);
        Whs[i] = h;
        Wls[i] = l;
    }
}

// ---------------------------------------------------------------------------
// Conv: fused(hi,lo planes)[b][hw][d] = relu(X^T W + coords + bias)
// A from GLOBAL directly (per-lane 8 strided dwords, split in reg) - no A LDS.
// B from pre-split Whs/Wls via gload_lds, double-buffered, 1 barrier/K-step.
// Grid 6144 = 3072 mtiles x 2 ntiles; ntile pair adjacent on same XCD so the
// second block's A reads hit L2.
// ---------------------------------------------------------------------------
__global__ __launch_bounds__(256, 3)
void conv_mfma_kernel(const float* __restrict__ input,
                      const unsigned short* __restrict__ Whs,
                      const unsigned short* __restrict__ Wls,
                      const float* __restrict__ convw,
                      const float* __restrict__ convb,
                      unsigned short* __restrict__ fhi,
                      unsigned short* __restrict__ flo) {
    __shared__ unsigned short Bh[2][4096];
    __shared__ unsigned short Bl[2][4096];

    const int tid = threadIdx.x;
    const int lane = tid & 63, wid = tid >> 6;
    const int wr = wid >> 1, wc = wid & 1;        // 2x2 waves, 64x64 each
    const int kq = lane >> 4, lr = lane & 15;

    const int xcd = blockIdx.x & 7;
    const int j = blockIdx.x >> 3;                // 0..767
    const int mtile = xcd * 384 + (j >> 1);       // 3072 mtiles, 384 per XCD
    const int ntile = j & 1;                      // pair adjacent on same XCD
    const int b = mtile / 3;
    const int hw0 = (mtile % 3) * 128;

    auto issue_B = [&](int ks, int buf) {
        const char* sh = (const char*)(Whs + (size_t)(ntile * 8 + ks) * 4096);
        const char* sl = (const char*)(Wls + (size_t)(ntile * 8 + ks) * 4096);
#pragma unroll
        for (int rd = 0; rd < 2; ++rd) {
            int o = tid * 16 + rd * 4096;
            gload16((char*)&Bh[buf][0] + o, sh + o);
            gload16((char*)&Bl[buf][0] + o, sl + o);
        }
    };

    f32x4 acc[4][4];
#pragma unroll
    for (int i = 0; i < 4; ++i)
#pragma unroll
        for (int jj = 0; jj < 4; ++jj) acc[i][jj] = (f32x4){0.f, 0.f, 0.f, 0.f};

    issue_B(0, 0);
    __syncthreads();

    const float* pabase = input + (size_t)b * (kC * kHW)
                          + (size_t)(kq * 8) * kHW + hw0 + wr * 64 + lr;

    for (int ks = 0; ks < 8; ++ks) {
        if (ks < 7) issue_B(ks + 1, (ks + 1) & 1);

        bf16x8 afh[4], afl[4];
#pragma unroll
        for (int fm = 0; fm < 4; ++fm) {
            const float* pa = pabase + (size_t)(ks * 32) * kHW + fm * 16;
            float v[8];
#pragma unroll
            for (int t = 0; t < 8; ++t) v[t] = pa[(size_t)t * kHW];
            union { unsigned u[4]; bf16x8 f; } ch, cl;
#pragma unroll
            for (int p = 0; p < 4; ++p) split2(v[2 * p], v[2 * p + 1], ch.u[p], cl.u[p]);
            afh[fm] = ch.f;
            afl[fm] = cl.f;
        }

        const int buf = ks & 1;
#pragma unroll
        for (int fn = 0; fn < 4; ++fn) {
            int n = wc * 64 + fn * 16 + lr;
            int a = n * 64 + ((16 * kq) ^ ((n & 3) << 4));
            bf16x8 bfh = *(const bf16x8*)((const char*)&Bh[buf][0] + a);
            bf16x8 bfl = *(const bf16x8*)((const char*)&Bl[buf][0] + a);
#pragma unroll
            for (int fm = 0; fm < 4; ++fm) {
                acc[fm][fn] = __builtin_amdgcn_mfma_f32_16x16x32_bf16(afh[fm], bfh, acc[fm][fn], 0, 0, 0);
                acc[fm][fn] = __builtin_amdgcn_mfma_f32_16x16x32_bf16(afl[fm], bfh, acc[fm][fn], 0, 0, 0);
                acc[fm][fn] = __builtin_amdgcn_mfma_f32_16x16x32_bf16(afh[fm], bfl, acc[fm][fn], 0, 0, 0);
            }
        }
        __syncthreads();
    }

    // epilogue: coords + bias + relu, split-store hi/lo planes
    float wxv[4], wyv[4], bbv[4];
    int dd[4];
#pragma unroll
    for (int fn = 0; fn < 4; ++fn) {
        dd[fn] = ntile * 128 + wc * 64 + fn * 16 + lr;
        wxv[fn] = convw[256 * 256 + dd[fn]];
        wyv[fn] = convw[257 * 256 + dd[fn]];
        bbv[fn] = convb[dd[fn]];
    }
#pragma unroll
    for (int fm = 0; fm < 4; ++fm)
#pragma unroll
        for (int r = 0; r < 4; ++r) {
            int hw = hw0 + wr * 64 + fm * 16 + kq * 4 + r;
            int row = hw / 24, col = hw % 24;
            float xc = (float)col * (1.0f / 23.0f);
            float yc = (float)row * (1.0f / 15.0f);
            size_t base = ((size_t)b * kHW + hw) * 256;
#pragma unroll
            for (int fn = 0; fn < 4; ++fn) {
                float v = acc[fm][fn][r] + wxv[fn] * xc + wyv[fn] * yc + bbv[fn];
                v = fmaxf(v, 0.0f);
                unsigned short h, l;
                split1(v, h, l);
                fhi[base + dd[fn]] = h;
                flo[base + dd[fn]] = l;
            }
        }
}

// ---------------------------------------------------------------------------
// Scene: per-batch block. MFMA scores -> softmax -> f32 vals -> reps -> o1/o2
// -> pair. q pre-split into fragment-order LDS (conflict-free b128 reads).
// LDS: sc(15.5K) + union(16K qfrags | 30K bufs) ~= 46KB -> 3 blocks/CU.
// ---------------------------------------------------------------------------
__global__ __launch_bounds__(256, 3)
void scene_kernel(const unsigned short* __restrict__ fhi,
                  const unsigned short* __restrict__ flo,
                  const int* __restrict__ lenRaw,
                  const float* __restrict__ query,
                  const float* __restrict__ featw,
                  const float* __restrict__ featb,
                  const float* __restrict__ o1w,
                  const float* __restrict__ o1b,
                  const float* __restrict__ o2w,
                  const float* __restrict__ o2b,
                  float* __restrict__ outReps,
                  float* __restrict__ outPair) {
    __shared__ float sc[kN][388];                  // padded: bank-spread
    __shared__ __align__(16) char U[30720];        // qfrags (16K) | bufA/R/C (30K)

    const int b = blockIdx.x, tid = threadIdx.x;
    const int lane = tid & 63, wv = tid >> 6;
    const int kq = lane >> 4, lr = lane & 15;

    const int is64 = (lenRaw[1] == 0) ? 1 : 0;     // int64 vs int32 layout
    const int len = is64 ? lenRaw[2 * b] : lenRaw[b];

    // phase 0: q -> fragment-order split LDS. entry e=(ks*64+l) holds
    // (n=l&15, k = ks*32 + (l>>4)*8 + j), zeros for n>=10.
    {
        uint4* qh_f = (uint4*)U;
        uint4* ql_f = (uint4*)(U + 8192);
        for (int e = tid; e < 512; e += 256) {
            int ks = e >> 6, l = e & 63;
            int kq_ = (l >> 4) & 3, n = l & 15;
            uint4 H = make_uint4(0, 0, 0, 0), L = make_uint4(0, 0, 0, 0);
            if (n < kN) {
                const float* qp = query + n * 256 + ks * 32 + kq_ * 8;
                unsigned h[4], lo_[4];
#pragma unroll
                for (int p = 0; p < 4; ++p) split2(qp[2 * p], qp[2 * p + 1], h[p], lo_[p]);
                H = make_uint4(h[0], h[1], h[2], h[3]);
                L = make_uint4(lo_[0], lo_[1], lo_[2], lo_[3]);
            }
            qh_f[e] = H;
            ql_f[e] = L;
        }
    }
    __syncthreads();

    // phase 1: scores via MFMA. wave wv owns hw rows [wv*96, wv*96+96).
    {
        const uint4* qh_f = (const uint4*)U;
        const uint4* ql_f = (const uint4*)(U + 8192);
        f32x4 acc[6];
#pragma unroll
        for (int i = 0; i < 6; ++i) acc[i] = (f32x4){0.f, 0.f, 0.f, 0.f};
        const unsigned short* pah = fhi + ((size_t)b * kHW + wv * 96 + lr) * 256 + kq * 8;
        const unsigned short* pal = flo + ((size_t)b * kHW + wv * 96 + lr) * 256 + kq * 8;
        for (int ks = 0; ks < 8; ++ks) {
            union { uint4 u; bf16x8 f; } qh, ql;
            qh.u = qh_f[ks * 64 + lane];
            ql.u = ql_f[ks * 64 + lane];
#pragma unroll
            for (int fm = 0; fm < 6; ++fm) {
                bf16x8 ah = *(const bf16x8*)(pah + (size_t)fm * 16 * 256 + ks * 32);
                bf16x8 al = *(const bf16x8*)(pal + (size_t)fm * 16 * 256 + ks * 32);
                acc[fm] = __builtin_amdgcn_mfma_f32_16x16x32_bf16(ah, qh.f, acc[fm], 0, 0, 0);
                acc[fm] = __builtin_amdgcn_mfma_f32_16x16x32_bf16(al, qh.f, acc[fm], 0, 0, 0);
                acc[fm] = __builtin_amdgcn_mfma_f32_16x16x32_bf16(ah, ql.f, acc[fm], 0, 0, 0);
            }
        }
        if (lr < kN) {
#pragma unroll
            for (int fm = 0; fm < 6; ++fm)
#pragma unroll
                for (int r = 0; r < 4; ++r)
                    sc[lr][wv * 96 + fm * 16 + kq * 4 + r] = acc[fm][r];
        }
    }
    __syncthreads();

    // phase 2: softmax over hw (wave per object)
    for (int n = wv; n < kN; n += 4) {
        float v6[6];
        float m = -1e30f;
#pragma unroll
        for (int i = 0; i < 6; ++i) { v6[i] = sc[n][lane + 64 * i]; m = fmaxf(m, v6[i]); }
#pragma unroll
        for (int off = 32; off >= 1; off >>= 1) m = fmaxf(m, __shfl_xor(m, off, 64));
        float s = 0.0f;
#pragma unroll
        for (int i = 0; i < 6; ++i) { v6[i] = __expf(v6[i] - m); s += v6[i]; }
#pragma unroll
        for (int off = 32; off >= 1; off >>= 1) s += __shfl_xor(s, off, 64);
        float inv = 1.0f / s;
#pragma unroll
        for (int i = 0; i < 6; ++i) sc[n][lane + 64 * i] = v6[i] * inv;
    }
    __syncthreads();

    // phase 3: vals[n][c] = sum_hw attn[n][hw]*fused[hw][c]  (thread = c, f32)
    {
        float va[kN];
#pragma unroll
        for (int n = 0; n < kN; ++n) va[n] = 0.0f;
        const unsigned short* ph = fhi + (size_t)b * kHW * 256 + tid;
        const unsigned short* pl = flo + (size_t)b * kHW * 256 + tid;
        for (int h4 = 0; h4 < kHW; h4 += 4) {
            float f0 = bfval(ph[(size_t)(h4 + 0) * 256]) + bfval(pl[(size_t)(h4 + 0) * 256]);
            float f1 = bfval(ph[(size_t)(h4 + 1) * 256]) + bfval(pl[(size_t)(h4 + 1) * 256]);
            float f2 = bfval(ph[(size_t)(h4 + 2) * 256]) + bfval(pl[(size_t)(h4 + 2) * 256]);
            float f3 = bfval(ph[(size_t)(h4 + 3) * 256]) + bfval(pl[(size_t)(h4 + 3) * 256]);
#pragma unroll
            for (int n = 0; n < kN; ++n) {
                float4 a4 = *(const float4*)&sc[n][h4];
                va[n] = fmaf(a4.x, f0, fmaf(a4.y, f1, fmaf(a4.z, f2, fmaf(a4.w, f3, va[n]))));
            }
        }
        float* bufA = (float*)U;
#pragma unroll
        for (int n = 0; n < kN; ++n) bufA[n * 256 + tid] = va[n];
    }
    __syncthreads();

    float* bufA = (float*)U;
    float* bufR = (float*)(U + 10240);
    float* bufC = (float*)(U + 20480);

    // phase 4: reps = relu(vals @ featw + featb)
    {
        float ra[kN];
        float fb0 = featb[tid];
#pragma unroll
        for (int n = 0; n < kN; ++n) ra[n] = fb0;
        for (int k = 0; k < 256; ++k) {
            float w = featw[k * 256 + tid];
#pragma unroll
            for (int n = 0; n < kN; ++n) ra[n] = fmaf(bufA[n * 256 + k], w, ra[n]);
        }
#pragma unroll
        for (int n = 0; n < kN; ++n) bufR[n * 256 + tid] = fmaxf(ra[n], 0.0f);
    }
    __syncthreads();

    // phase 5: L2-normalize + ragged mask + write reps
    {
        float4* r4 = reinterpret_cast<float4*>(bufR);
        float4* or4 = reinterpret_cast<float4*>(outReps + (size_t)b * kN * 256);
        for (int n = wv; n < kN; n += 4) {
            float4 r = r4[n * 64 + lane];
            float ss = r.x * r.x + r.y * r.y + r.z * r.z + r.w * r.w;
#pragma unroll
            for (int off = 32; off >= 1; off >>= 1) ss += __shfl_xor(ss, off, 64);
            float norm = sqrtf(ss);
            float scale = (n < len) ? (1.0f / fmaxf(norm, 1e-12f)) : 0.0f;
            r.x *= scale; r.y *= scale; r.z *= scale; r.w *= scale;
            r4[n * 64 + lane] = r;
            or4[n * 64 + lane] = r;
        }
    }
    __syncthreads();

    // phase 6: o1 -> bufA, o2 -> bufC
    {
        float a1[kN], a2[kN];
        float b1 = o1b[tid], b2 = o2b[tid];
#pragma unroll
        for (int n = 0; n < kN; ++n) { a1[n] = b1; a2[n] = b2; }
        for (int k = 0; k < 256; ++k) {
            float w1 = o1w[k * 256 + tid];
            float w2 = o2w[k * 256 + tid];
#pragma unroll
            for (int n = 0; n < kN; ++n) {
                float r = bufR[n * 256 + k];
                a1[n] = fmaf(r, w1, a1[n]);
                a2[n] = fmaf(r, w2, a2[n]);
            }
        }
#pragma unroll
        for (int n = 0; n < kN; ++n) { bufA[n * 256 + tid] = a1[n]; bufC[n * 256 + tid] = a2[n]; }
    }
    __syncthreads();

    // phase 7: pair[i][j][d]
    {
        float* pb = outPair + (size_t)b * kN * kN * 256;
#pragma unroll
        for (int i = 0; i < kN; ++i) {
            float o1v = bufA[i * 256 + tid];
            bool mvalid = (i < len);
#pragma unroll
            for (int jo = 0; jo < kN; ++jo) {
                float v = (mvalid && (jo < len)) ? (o1v + bufC[jo * 256 + tid]) : 0.0f;
                pb[(size_t)(i * kN + jo) * 256 + tid] = v;
            }
        }
    }
}

extern "C" void kernel_launch(void* const* d_in, const int* in_sizes, int n_in,
                              void* d_out, int out_size, void* d_ws, size_t ws_size,
                              hipStream_t stream) {
    const float* input  = (const float*)d_in[0];
    const int*   lenRaw = (const int*)d_in[2];
    const float* query  = (const float*)d_in[3];
    const float* convw  = (const float*)d_in[4];
    const float* convb  = (const float*)d_in[5];
    const float* featw  = (const float*)d_in[6];
    const float* featb  = (const float*)d_in[7];
    const float* o1w    = (const float*)d_in[8];
    const float* o1b    = (const float*)d_in[9];
    const float* o2w    = (const float*)d_in[10];
    const float* o2b    = (const float*)d_in[11];

    unsigned short* fhi = (unsigned short*)d_ws;     // hi plane, 201.3 MB
    unsigned short* flo = fhi + kPlane;              // lo plane, 201.3 MB
    float* outReps = (float*)d_out;
    float* outPair = outReps + (size_t)kB * kN * kD;

    // W split scratch parked in pair region (consumed by conv before scene
    // overwrites all of pair; stream-ordered).
    unsigned short* Whs = (unsigned short*)outPair;
    unsigned short* Wls = Whs + 65536;

    wprep_kernel<<<64, 256, 0, stream>>>(convw, Whs, Wls);
    conv_mfma_kernel<<<6144, 256, 0, stream>>>(input, Whs, Wls, convw, convb, fhi, flo);
    scene_kernel<<<kB, 256, 0, stream>>>(fhi, flo, lenRaw, query, featw, featb,
                                         o1w, o1b, o2w, o2b, outReps, outPair);
}